// Round 1
// baseline (159.387 us; speedup 1.0000x reference)
//
#include <hip/hip_runtime.h>

// RegionPartitioner: x (8,4,500,500) f32, step=32, region=64, edge-pad to 512.
// Out: (8, 225, 4, 64, 64) f32.  out[b,r,c,rr,rc] = x[b,c,min(32*(r/15)+rr,499),
//                                                      min(32*(r%15)+rc,499)]
// Pure gather: one thread per output float4 (rc chunk of 4). Output float4 is
// 16B-aligned (rc%4==0); stores perfectly coalesced. Input reads scalar
// (row stride 500 breaks 16B alignment) with edge clamp via min().

#define NB 8
#define NC 4
#define HW 500
#define RS 64
#define NT 15            // region starts per dim: 0,32,...,448
#define NREG (NT * NT)   // 225

__global__ __launch_bounds__(256) void region_partition_kernel(
    const float* __restrict__ x, float* __restrict__ out, int total4) {
    int tid = blockIdx.x * blockDim.x + threadIdx.x;
    if (tid >= total4) return;

    // out layout: b, r, c, rr, rc  (rc packed as 16 float4 per 64-row)
    int rc4 = tid & 15;              // which float4 within the 64-wide row
    int t   = tid >> 4;
    int rr  = t & 63;
    t >>= 6;
    int c   = t & 3;
    t >>= 2;
    int r   = t % NREG;
    int b   = t / NREG;

    int ti = r / NT;
    int tj = r - ti * NT;

    int row = ti * 32 + rr;
    row = min(row, HW - 1);          // edge pad (replicate last row)
    int colbase = tj * 32 + rc4 * 4;

    const float* src = x + ((size_t)(b * NC + c) * HW + row) * HW;

    float4 v;
    v.x = src[min(colbase + 0, HW - 1)];
    v.y = src[min(colbase + 1, HW - 1)];
    v.z = src[min(colbase + 2, HW - 1)];
    v.w = src[min(colbase + 3, HW - 1)];

    reinterpret_cast<float4*>(out)[tid] = v;
}

extern "C" void kernel_launch(void* const* d_in, const int* in_sizes, int n_in,
                              void* d_out, int out_size, void* d_ws, size_t ws_size,
                              hipStream_t stream) {
    const float* x = (const float*)d_in[0];
    float* out = (float*)d_out;

    const int total4 = NB * NREG * NC * RS * (RS / 4);  // 7,372,800
    const int block = 256;
    const int grid = (total4 + block - 1) / block;      // 28,800
    region_partition_kernel<<<grid, block, 0, stream>>>(x, out, total4);
}

// Round 2
// 150.449 us; speedup vs baseline: 1.0594x; 1.0594x over previous
//
#include <hip/hip_runtime.h>

// RegionPartitioner: x (8,4,500,500) f32, step=32, region=64, edge-pad to 512.
// Out: (8, 225, 4, 64, 64) f32.  out[b,r,c,rr,rc] = x[b,c,min(32*(r/15)+rr,499),
//                                                      min(32*(r%15)+rc,499)]
//
// R1: one block per region (b,r,c). 256 threads x 4 iters cover the 64x64 tile
// as 1024 float4 chunks. Row stride = 500 floats = 2000 B = 125*16 B, so every
// row start is 16B-aligned and the 4-wide read is ONE aligned float4 load when
// colbase <= 496. colbase >= 500 (tj==14, rc4 >= 13 only) is fully edge-clamped
// -> scalar load of col 499, splat. All (b,r,c,ti,tj) math is wave-uniform
// (from blockIdx) -> scalar pipe.

#define NB 8
#define NC 4
#define HW 500
#define RS 64
#define NT 15            // region starts per dim: 0,32,...,448
#define NREG (NT * NT)   // 225

__global__ __launch_bounds__(256) void region_partition_kernel(
    const float* __restrict__ x, float* __restrict__ out) {
    int bx = blockIdx.x;             // 0..7199 = (b*225 + r)*4 + c
    int c  = bx & 3;
    int br = bx >> 2;                // b*225 + r
    int b  = br / NREG;
    int r  = br - b * NREG;
    int ti = r / NT;
    int tj = r - ti * NT;

    int tid = threadIdx.x;
    int rc4 = tid & 15;              // float4 chunk within 64-wide row
    int rr0 = tid >> 4;              // 0..15

    int colbase = tj * 32 + rc4 * 4; // multiple of 4; <=496 or >=500
    const float* plane = x + (size_t)(b * NC + c) * (HW * HW);
    float4* dst = reinterpret_cast<float4*>(out)
                + (size_t)((b * NREG + r) * NC + c) * (RS * RS / 4);

    const bool clean = (colbase + 3 < HW);

    #pragma unroll
    for (int i = 0; i < 4; ++i) {
        int rr  = rr0 + 16 * i;
        int row = min(ti * 32 + rr, HW - 1);   // edge pad (replicate last row)
        const float* src = plane + (size_t)row * HW;
        float4 v;
        if (clean) {
            v = *reinterpret_cast<const float4*>(src + colbase);
        } else {
            float s = src[HW - 1];             // cols 500..511 all clamp to 499
            v = make_float4(s, s, s, s);
        }
        dst[rr * 16 + rc4] = v;                // wave: 64 consecutive float4s
    }
}

extern "C" void kernel_launch(void* const* d_in, const int* in_sizes, int n_in,
                              void* d_out, int out_size, void* d_ws, size_t ws_size,
                              hipStream_t stream) {
    const float* x = (const float*)d_in[0];
    float* out = (float*)d_out;

    const int grid = NB * NREG * NC;   // 7200 blocks, one region each
    region_partition_kernel<<<grid, 256, 0, stream>>>(x, out);
}